// Round 5
// baseline (328.622 us; speedup 1.0000x reference)
//
#include <hip/hip_runtime.h>
#include <hip/hip_bf16.h>
#include <cstdint>

// VanillaLSTMCell: B=8192, I=H=1024.
// z = [x|h] @ [Wx;Wh]^T + b  (M=8192, N=4096, K=2048), LSTM pointwise fused.
//
// ROUND 9: m201-style phase-locked schedule (T3+T4+T5) on the fragment-major
// layout. Per BK=32 tile: 2 phases, each {ds_read subtile (8 or 4 b128) ||
// stage 2 gload_lds -> barrier -> setprio(1) + 16 MFMA + setprio(0) ->
// barrier}; depth-3 tile prefetch over 4x32KB LDS bufs; vmcnt(8) ONCE per
// tile at the seam (never 0 in steady state). Round-8's lockstep
// [12 reads][32 MFMA] alternation was the diagnosed loss (39% MfmaUtil, no
// pipe saturated); m201 measured 62% at this exact geometry.
// Reads are contiguous b128 (conflict-free by construction, no swizzle).
// MFMA accumulation order unchanged -> bit-identical to round 8.

typedef __bf16 bf16;
typedef __attribute__((ext_vector_type(8))) bf16 bf16x8;
typedef __attribute__((ext_vector_type(4))) float f32x4;

#define CN_OFF 8388608  // 8192*1024, c_next offset in d_out

__device__ __forceinline__ void gload16(const bf16* g, bf16* l) {
  __builtin_amdgcn_global_load_lds(
      (const __attribute__((address_space(1))) void*)g,
      (__attribute__((address_space(3))) void*)l, 16, 0, 0);
}

__device__ __forceinline__ bf16x8 cvt8(f32x4 v0, f32x4 v1) {
  bf16x8 o;
  o[0]=(bf16)v0[0]; o[1]=(bf16)v0[1]; o[2]=(bf16)v0[2]; o[3]=(bf16)v0[3];
  o[4]=(bf16)v1[0]; o[5]=(bf16)v1[1]; o[6]=(bf16)v1[2]; o[7]=(bf16)v1[3];
  return o;
}

// ---- pack: coalesced read -> LDS transpose -> coalesced fragment write ----
// A2[mb(64)][kt(64)][wm(2)][mi(4)][lane(64)][8]:
//   m = mb*128 + wm*64 + mi*16 + (lane&15), k = kt*32 + (lane>>4)*8
// B2[nb(32)][kt(64)][wn(2)][gate(4)][lane(64)][8]:
//   j = (nb*2+wn)*16 + (lane&15), k = kt*32 + (lane>>4)*8
__global__ __launch_bounds__(256) void pack_all(
    const float* __restrict__ x, const float* __restrict__ h,
    const float* __restrict__ wxi, const float* __restrict__ whi,
    const float* __restrict__ wxf, const float* __restrict__ whf,
    const float* __restrict__ wxo, const float* __restrict__ who,
    const float* __restrict__ wxg, const float* __restrict__ whg,
    const float* __restrict__ bxi, const float* __restrict__ bhi,
    const float* __restrict__ bxf, const float* __restrict__ bhf,
    const float* __restrict__ bxo, const float* __restrict__ bho,
    const float* __restrict__ bxg, const float* __restrict__ bhg,
    bf16* __restrict__ A2, bf16* __restrict__ B2, float* __restrict__ Bcomb) {
  __shared__ __align__(16) bf16 lds[8192];   // 16KB: [row][128] with XOR swizzle
  const int t = threadIdx.x;
  const int bid = blockIdx.x;

  if (bid < 2048) {
    // ---- A side ----
    const int mb = bid >> 5;
    const int wm = (bid >> 4) & 1;
    const int q  = bid & 15;                 // kt-quad: cols [q*128, q*128+128)
    const int rowbase = mb * 128 + wm * 64;
    const float* srcM; int k0;
    if (q < 8) { srcM = x; k0 = q * 128; } else { srcM = h; k0 = q * 128 - 1024; }
#pragma unroll
    for (int r = 0; r < 4; ++r) {
      const int rl = r * 16 + (t >> 4);      // 0..63
      const int cc = (t & 15) * 8;           // 0..120
      const float* s = srcM + (size_t)(rowbase + rl) * 1024 + k0 + cc;
      f32x4 v0 = *(const f32x4*)s;
      f32x4 v1 = *(const f32x4*)(s + 4);
      const int chunkS = (t & 15) ^ (rl & 7);
      *(bf16x8*)((char*)lds + rl * 256 + chunkS * 16) = cvt8(v0, v1);
    }
    __syncthreads();
#pragma unroll
    for (int r = 0; r < 4; ++r) {
      const int idx = r * 256 + t;           // 0..1023
      const int fj  = idx >> 6;              // 0..15 = ktL*4 + mi
      const int ktL = fj >> 2, mi = fj & 3;
      const int l   = idx & 63;
      const int srow = mi * 16 + (l & 15);
      const int chunkS = (ktL * 4 + (l >> 4)) ^ (srow & 7);
      bf16x8 o = *(const bf16x8*)((const char*)lds + srow * 256 + chunkS * 16);
      size_t el = ((size_t)mb * 64 + q * 4 + ktL) * 4096 + (size_t)wm * 2048 + mi * 512 + l * 8;
      *(bf16x8*)(A2 + el) = o;
    }
  } else {
    // ---- B (weights) side ----
    const int bid2 = bid - 2048;
    const int nb   = bid2 >> 6;
    const int gate = (bid2 >> 4) & 3;
    const int q    = bid2 & 15;
    const float* wxm = (gate == 0) ? wxi : (gate == 1) ? wxf : (gate == 2) ? wxo : wxg;
    const float* whm = (gate == 0) ? whi : (gate == 1) ? whf : (gate == 2) ? who : whg;
    const float* srcM; int k0;
    if (q < 8) { srcM = wxm; k0 = q * 128; } else { srcM = whm; k0 = q * 128 - 1024; }
    const int jbase = nb * 32;
#pragma unroll
    for (int r = 0; r < 2; ++r) {
      const int rl = r * 16 + (t >> 4);      // 0..31
      const int cc = (t & 15) * 8;
      const float* s = srcM + (size_t)(jbase + rl) * 1024 + k0 + cc;
      f32x4 v0 = *(const f32x4*)s;
      f32x4 v1 = *(const f32x4*)(s + 4);
      const int chunkS = (t & 15) ^ (rl & 7);
      *(bf16x8*)((char*)lds + rl * 256 + chunkS * 16) = cvt8(v0, v1);
    }
    __syncthreads();
#pragma unroll
    for (int r = 0; r < 2; ++r) {
      const int idx = r * 256 + t;           // 0..511
      const int fj  = idx >> 6;              // 0..7 = ktL*2 + wn
      const int ktL = fj >> 1, wn = fj & 1;
      const int l   = idx & 63;
      const int srow = wn * 16 + (l & 15);
      const int chunkS = (ktL * 4 + (l >> 4)) ^ (srow & 7);
      bf16x8 o = *(const bf16x8*)((const char*)lds + srow * 256 + chunkS * 16);
      size_t el = ((size_t)nb * 64 + q * 4 + ktL) * 4096 + (size_t)wn * 2048 + gate * 512 + l * 8;
      *(bf16x8*)(B2 + el) = o;
    }
    if (q == 0 && t < 32) {
      const float* bxv = (gate == 0) ? bxi : (gate == 1) ? bxf : (gate == 2) ? bxo : bxg;
      const float* bhv = (gate == 0) ? bhi : (gate == 1) ? bhf : (gate == 2) ? bho : bhg;
      const int wn = t >> 4, jl = t & 15;
      const int j = nb * 32 + wn * 16 + jl;
      Bcomb[(nb * 2 + wn) * 64 + gate * 16 + jl] = bxv[j] + bhv[j];
    }
  }
}

__device__ __forceinline__ float sigf(float v) { return 1.f / (1.f + __expf(-v)); }
__device__ __forceinline__ float tanhfast(float v) {
  v = fminf(15.f, fmaxf(-15.f, v));
  float e = __expf(2.f * v);
  return (e - 1.f) / (e + 1.f);
}

// ---- 256x256 LDS-shared GEMM, m201 phase-locked pipeline ----
// Wave (wr,wc): wr in {0,1} selects mb unit; wc: nbL = wc>>1, wn = wc&1.
// 4 LDS bufs x 16384 elems; tile kt lives in buf[kt&3]; depth-3 prefetch
// (stage kt+3 during tile kt). vmcnt(8) once per tile seam (tail: 4, 0).
__global__ __launch_bounds__(512, 2) void gemm_lstm(const bf16* __restrict__ A2,
                                                    const bf16* __restrict__ B2,
                                                    const float* __restrict__ Bcomb,
                                                    const float* __restrict__ c,
                                                    float* __restrict__ out) {
  __shared__ __align__(16) bf16 lds[65536];   // 128KB = 4 buf x 16384 elems
  const int t    = threadIdx.x;
  const int wave = t >> 6;
  const int lane = t & 63;

  // XCD swizzle: xcd owns bn pair {2x,2x+1} (B2 slice 2MB -> L2-resident).
  const int bid = blockIdx.x;          // 512 blocks
  const int xcd = bid & 7;
  const int idx = bid >> 3;            // 0..63
  const int bn  = xcd * 2 + (idx & 1); // 0..15
  const int bm  = idx >> 1;            // 0..31

  const int wr  = wave >> 2;           // 0..1: mb unit
  const int wc  = wave & 3;            // 0..3
  const int nbL = wc >> 1, wn = wc & 1;
  const int lrow = lane & 15, lkg = lane >> 4;

  const int tEl = t * 8;               // thread's element in a 4096-elem region
  const int wEl = (t & ~63) * 8;       // wave-uniform LDS base element

  const bf16* aSrc0 = A2 + (size_t)(2 * bm)     * 64 * 4096;
  const bf16* aSrc1 = A2 + (size_t)(2 * bm + 1) * 64 * 4096;
  const bf16* bSrc0 = B2 + (size_t)(2 * bn)     * 64 * 4096;
  const bf16* bSrc1 = B2 + (size_t)(2 * bn + 1) * 64 * 4096;

  // buf layout (16384 elems): [A-mb0: 4096][A-mb1: 4096][B-nb0: 4096][B-nb1: 4096]
  auto stageHalf = [&](int tile, int half) {
    const size_t kOff = (size_t)tile * 4096;
    bf16* d = lds + (tile & 3) * 16384;
    if (half == 0) {
      gload16(aSrc0 + kOff + tEl, d +        wEl);
      gload16(aSrc1 + kOff + tEl, d + 4096 + wEl);
    } else {
      gload16(bSrc0 + kOff + tEl, d +  8192 + wEl);
      gload16(bSrc1 + kOff + tEl, d + 12288 + wEl);
    }
  };

  f32x4 acc[8][4] = {};   // acc[amI][gate]

  // prologue: 3 tiles in flight (12 loads); retire tile 0 (vmcnt 8).
  stageHalf(0, 0); stageHalf(0, 1);
  stageHalf(1, 0); stageHalf(1, 1);
  stageHalf(2, 0); stageHalf(2, 1);
  asm volatile("s_waitcnt vmcnt(8)" ::: "memory");
  __builtin_amdgcn_s_barrier();

#pragma unroll 1
  for (int kt = 0; kt < 64; ++kt) {
    const int p = kt & 3;
    const bf16* bufA = lds + p * 16384 + wr * 4096;
    const bf16* bufB = lds + p * 16384 + 8192 + nbL * 4096 + wn * 2048;
    bf16x8 af[8], bfr[4];

    // ---- phase 0: reads (af0-3, bfr0-3) || stage A-half of kt+3 ----
#pragma unroll
    for (int i = 0; i < 4; ++i)
      af[i] = *(const bf16x8*)(bufA + i * 512 + lane * 8);
#pragma unroll
    for (int g = 0; g < 4; ++g)
      bfr[g] = *(const bf16x8*)(bufB + g * 512 + lane * 8);
    if (kt <= 60) stageHalf(kt + 3, 0);
    __builtin_amdgcn_s_barrier();
    __builtin_amdgcn_s_setprio(1);
#pragma unroll
    for (int i = 0; i < 4; ++i)
#pragma unroll
      for (int g = 0; g < 4; ++g)
        acc[i][g] = __builtin_amdgcn_mfma_f32_16x16x32_bf16(af[i], bfr[g], acc[i][g], 0, 0, 0);
    __builtin_amdgcn_s_setprio(0);
    __builtin_amdgcn_s_barrier();

    // ---- phase 1: reads (af4-7) || stage B-half of kt+3 ----
#pragma unroll
    for (int i = 4; i < 8; ++i)
      af[i] = *(const bf16x8*)(bufA + i * 512 + lane * 8);
    if (kt <= 60) stageHalf(kt + 3, 1);
    __builtin_amdgcn_s_barrier();
    __builtin_amdgcn_s_setprio(1);
#pragma unroll
    for (int i = 4; i < 8; ++i)
#pragma unroll
      for (int g = 0; g < 4; ++g)
        acc[i][g] = __builtin_amdgcn_mfma_f32_16x16x32_bf16(af[i], bfr[g], acc[i][g], 0, 0, 0);
    __builtin_amdgcn_s_setprio(0);

    // tile seam: retire tile kt+1 so its reads are safe after the barrier.
    if (kt <= 60)      asm volatile("s_waitcnt vmcnt(8)" ::: "memory");
    else if (kt == 61) asm volatile("s_waitcnt vmcnt(4)" ::: "memory");
    else if (kt == 62) asm volatile("s_waitcnt vmcnt(0)" ::: "memory");
    if (kt < 63) __builtin_amdgcn_s_barrier();
  }

  // ---- register-resident LSTM epilogue ----
  const int nb = bn * 2 + nbL;
  const int jg = (nb * 2 + wn) * 16 + lrow;
  const int bbase = (nb * 2 + wn) * 64 + lrow;
  const float bi  = Bcomb[bbase +  0];
  const float bf_ = Bcomb[bbase + 16];
  const float bo  = Bcomb[bbase + 32];
  const float bg  = Bcomb[bbase + 48];

#pragma unroll
  for (int i = 0; i < 8; ++i) {
    const int row0 = (2 * bm + wr) * 128 + (i >> 2) * 64 + (i & 3) * 16 + lkg * 4;
    float cv[4];
#pragma unroll
    for (int r = 0; r < 4; ++r)
      cv[r] = c[(size_t)(row0 + r) * 1024 + jg];
#pragma unroll
    for (int r = 0; r < 4; ++r) {
      float zi = acc[i][0][r] + bi;
      float zf = acc[i][1][r] + bf_;
      float zo = acc[i][2][r] + bo;
      float zg = acc[i][3][r] + bg;
      float it = sigf(zi), ft = sigf(zf), ot = sigf(zo), gt = tanhfast(zg);
      float cn = ft * cv[r] + it * gt;
      size_t off = (size_t)(row0 + r) * 1024 + jg;
      out[off] = ot * tanhfast(cn);        // h_next
      out[CN_OFF + off] = cn;              // c_next
    }
  }
}

extern "C" void kernel_launch(void* const* d_in, const int* in_sizes, int n_in,
                              void* d_out, int out_size, void* d_ws, size_t ws_size,
                              hipStream_t stream) {
  const float* x   = (const float*)d_in[0];
  const float* h   = (const float*)d_in[1];
  const float* c   = (const float*)d_in[2];
  const float* Wxi = (const float*)d_in[3];  const float* bxi = (const float*)d_in[4];
  const float* Whi = (const float*)d_in[5];  const float* bhi = (const float*)d_in[6];
  const float* Wxf = (const float*)d_in[7];  const float* bxf = (const float*)d_in[8];
  const float* Whf = (const float*)d_in[9];  const float* bhf = (const float*)d_in[10];
  const float* Wxo = (const float*)d_in[11]; const float* bxo = (const float*)d_in[12];
  const float* Who = (const float*)d_in[13]; const float* bho = (const float*)d_in[14];
  const float* Wxg = (const float*)d_in[15]; const float* bxg = (const float*)d_in[16];
  const float* Whg = (const float*)d_in[17]; const float* bhg = (const float*)d_in[18];
  float* out = (float*)d_out;

  bf16*  Abuf  = (bf16*)d_ws;                          // 32 MB
  bf16*  Wbuf  = Abuf + (size_t)8192 * 2048;           // 16 MB
  float* Bcomb = (float*)(Wbuf + (size_t)4096 * 2048); // 16 KB

  pack_all<<<4096, 256, 0, stream>>>(x, h,
                                     Wxi, Whi, Wxf, Whf, Wxo, Who, Wxg, Whg,
                                     bxi, bhi, bxf, bhf, bxo, bho, bxg, bhg,
                                     Abuf, Wbuf, Bcomb);
  gemm_lstm<<<512, 512, 0, stream>>>(Abuf, Wbuf, Bcomb, c, out);
}

// Round 6
// 314.667 us; speedup vs baseline: 1.0443x; 1.0443x over previous
//
#include <hip/hip_runtime.h>
#include <hip/hip_bf16.h>
#include <cstdint>

// VanillaLSTMCell: B=8192, I=H=1024.
// z = [x|h] @ [Wx;Wh]^T + b  (M=8192, N=4096, K=2048), LSTM pointwise fused.
//
// ROUND 10: occupancy-for-overlap. R7-R9 showed both pipes ~45% busy and
// non-overlapped at 2 waves/SIMD; barriers hurt monotonically. Fix: 2 blocks
// per CU (4 waves/SIMD) so cross-BLOCK TLP fills barrier/drain bubbles
// (m97/m114 mechanism). Wave tile 64x64 (acc=64 VGPR), block 512thr/8 waves,
// tile 256x128, BK=32, 3 LDS bufs x 24KB = 72KB (2 blocks/CU by LDS),
// __launch_bounds__(512,4) caps VGPR at 128. R8's race-proven skeleton:
// wait vmcnt(3) BEFORE the single per-iter barrier (3 bufs -> never drain
// in steady state), stage depth-2. Fragment-major b128 reads, 0 conflicts.

typedef __bf16 bf16;
typedef __attribute__((ext_vector_type(8))) bf16 bf16x8;
typedef __attribute__((ext_vector_type(4))) float f32x4;

#define CN_OFF 8388608  // 8192*1024, c_next offset in d_out

__device__ __forceinline__ void gload16(const bf16* g, bf16* l) {
  __builtin_amdgcn_global_load_lds(
      (const __attribute__((address_space(1))) void*)g,
      (__attribute__((address_space(3))) void*)l, 16, 0, 0);
}

__device__ __forceinline__ bf16x8 cvt8(f32x4 v0, f32x4 v1) {
  bf16x8 o;
  o[0]=(bf16)v0[0]; o[1]=(bf16)v0[1]; o[2]=(bf16)v0[2]; o[3]=(bf16)v0[3];
  o[4]=(bf16)v1[0]; o[5]=(bf16)v1[1]; o[6]=(bf16)v1[2]; o[7]=(bf16)v1[3];
  return o;
}

// ---- pack: coalesced read -> LDS transpose -> coalesced fragment write ----
// A2[mb(64)][kt(64)][wm(2)][mi(4)][lane(64)][8]:
//   m = mb*128 + wm*64 + mi*16 + (lane&15), k = kt*32 + (lane>>4)*8
// B2[nb(32)][kt(64)][wn(2)][gate(4)][lane(64)][8]:
//   j = (nb*2+wn)*16 + (lane&15), k = kt*32 + (lane>>4)*8
__global__ __launch_bounds__(256) void pack_all(
    const float* __restrict__ x, const float* __restrict__ h,
    const float* __restrict__ wxi, const float* __restrict__ whi,
    const float* __restrict__ wxf, const float* __restrict__ whf,
    const float* __restrict__ wxo, const float* __restrict__ who,
    const float* __restrict__ wxg, const float* __restrict__ whg,
    const float* __restrict__ bxi, const float* __restrict__ bhi,
    const float* __restrict__ bxf, const float* __restrict__ bhf,
    const float* __restrict__ bxo, const float* __restrict__ bho,
    const float* __restrict__ bxg, const float* __restrict__ bhg,
    bf16* __restrict__ A2, bf16* __restrict__ B2, float* __restrict__ Bcomb) {
  __shared__ __align__(16) bf16 lds[8192];   // 16KB: [row][128] with XOR swizzle
  const int t = threadIdx.x;
  const int bid = blockIdx.x;

  if (bid < 2048) {
    // ---- A side ----
    const int mb = bid >> 5;
    const int wm = (bid >> 4) & 1;
    const int q  = bid & 15;                 // kt-quad: cols [q*128, q*128+128)
    const int rowbase = mb * 128 + wm * 64;
    const float* srcM; int k0;
    if (q < 8) { srcM = x; k0 = q * 128; } else { srcM = h; k0 = q * 128 - 1024; }
#pragma unroll
    for (int r = 0; r < 4; ++r) {
      const int rl = r * 16 + (t >> 4);      // 0..63
      const int cc = (t & 15) * 8;           // 0..120
      const float* s = srcM + (size_t)(rowbase + rl) * 1024 + k0 + cc;
      f32x4 v0 = *(const f32x4*)s;
      f32x4 v1 = *(const f32x4*)(s + 4);
      const int chunkS = (t & 15) ^ (rl & 7);
      *(bf16x8*)((char*)lds + rl * 256 + chunkS * 16) = cvt8(v0, v1);
    }
    __syncthreads();
#pragma unroll
    for (int r = 0; r < 4; ++r) {
      const int idx = r * 256 + t;           // 0..1023
      const int fj  = idx >> 6;              // 0..15 = ktL*4 + mi
      const int ktL = fj >> 2, mi = fj & 3;
      const int l   = idx & 63;
      const int srow = mi * 16 + (l & 15);
      const int chunkS = (ktL * 4 + (l >> 4)) ^ (srow & 7);
      bf16x8 o = *(const bf16x8*)((const char*)lds + srow * 256 + chunkS * 16);
      size_t el = ((size_t)mb * 64 + q * 4 + ktL) * 4096 + (size_t)wm * 2048 + mi * 512 + l * 8;
      *(bf16x8*)(A2 + el) = o;
    }
  } else {
    // ---- B (weights) side ----
    const int bid2 = bid - 2048;
    const int nb   = bid2 >> 6;
    const int gate = (bid2 >> 4) & 3;
    const int q    = bid2 & 15;
    const float* wxm = (gate == 0) ? wxi : (gate == 1) ? wxf : (gate == 2) ? wxo : wxg;
    const float* whm = (gate == 0) ? whi : (gate == 1) ? whf : (gate == 2) ? who : whg;
    const float* srcM; int k0;
    if (q < 8) { srcM = wxm; k0 = q * 128; } else { srcM = whm; k0 = q * 128 - 1024; }
    const int jbase = nb * 32;
#pragma unroll
    for (int r = 0; r < 2; ++r) {
      const int rl = r * 16 + (t >> 4);      // 0..31
      const int cc = (t & 15) * 8;
      const float* s = srcM + (size_t)(jbase + rl) * 1024 + k0 + cc;
      f32x4 v0 = *(const f32x4*)s;
      f32x4 v1 = *(const f32x4*)(s + 4);
      const int chunkS = (t & 15) ^ (rl & 7);
      *(bf16x8*)((char*)lds + rl * 256 + chunkS * 16) = cvt8(v0, v1);
    }
    __syncthreads();
#pragma unroll
    for (int r = 0; r < 2; ++r) {
      const int idx = r * 256 + t;           // 0..511
      const int fj  = idx >> 6;              // 0..7 = ktL*2 + wn
      const int ktL = fj >> 1, wn = fj & 1;
      const int l   = idx & 63;
      const int srow = wn * 16 + (l & 15);
      const int chunkS = (ktL * 4 + (l >> 4)) ^ (srow & 7);
      bf16x8 o = *(const bf16x8*)((const char*)lds + srow * 256 + chunkS * 16);
      size_t el = ((size_t)nb * 64 + q * 4 + ktL) * 4096 + (size_t)wn * 2048 + gate * 512 + l * 8;
      *(bf16x8*)(B2 + el) = o;
    }
    if (q == 0 && t < 32) {
      const float* bxv = (gate == 0) ? bxi : (gate == 1) ? bxf : (gate == 2) ? bxo : bxg;
      const float* bhv = (gate == 0) ? bhi : (gate == 1) ? bhf : (gate == 2) ? bho : bhg;
      const int wn = t >> 4, jl = t & 15;
      const int j = nb * 32 + wn * 16 + jl;
      Bcomb[(nb * 2 + wn) * 64 + gate * 16 + jl] = bxv[j] + bhv[j];
    }
  }
}

__device__ __forceinline__ float sigf(float v) { return 1.f / (1.f + __expf(-v)); }
__device__ __forceinline__ float tanhfast(float v) {
  v = fminf(15.f, fmaxf(-15.f, v));
  float e = __expf(2.f * v);
  return (e - 1.f) / (e + 1.f);
}

// ---- 256x128 LDS-shared GEMM, 2 blocks/CU, 3-buf counted-vmcnt ----
// Block: rows [bm*256,+256) (mb units 2bm,2bm+1), one nb unit (128 z-cols).
// 8 waves (wr 0..3, wn 0..1): wave = 64 rows x 64 z-cols, acc[4][4] f32x4.
// Per kt (BK=32): wait vmcnt(3) -> barrier -> stage(kt+2,3 gloads) ->
// 8 ds_read_b128 -> 16 MFMA. Loads never drain to 0 until the tail.
__global__ __launch_bounds__(512, 4) void gemm_lstm(const bf16* __restrict__ A2,
                                                    const bf16* __restrict__ B2,
                                                    const float* __restrict__ Bcomb,
                                                    const float* __restrict__ c,
                                                    float* __restrict__ out) {
  __shared__ __align__(16) bf16 lds[36864];   // 72KB = 3 bufs x 12288 elems
  const int t    = threadIdx.x;
  const int wave = t >> 6;
  const int lane = t & 63;

  // XCD swizzle: xcd owns nb in [4x,4x+4) -> 2MB B2 slice L2-resident.
  const int bid = blockIdx.x;          // 1024 blocks
  const int xcd = bid & 7;
  const int idx = bid >> 3;            // 0..127
  const int nb  = xcd * 4 + (idx & 3); // 0..31
  const int bm  = idx >> 2;            // 0..31

  const int wr  = wave >> 1;           // 0..3
  const int wn  = wave & 1;            // 0..1
  const int mbU = wr >> 1, wm = wr & 1;
  const int lrow = lane & 15, lkg = lane >> 4;

  const int tEl = t * 8;               // thread's element in a 4096-elem region
  const int wEl = (t & ~63) * 8;       // wave-uniform LDS base element

  const bf16* aSrc0 = A2 + (size_t)(2 * bm)     * 64 * 4096;
  const bf16* aSrc1 = A2 + (size_t)(2 * bm + 1) * 64 * 4096;
  const bf16* bSrc  = B2 + (size_t)nb           * 64 * 4096;

  // buf layout (12288 elems): [A-mbU0: 4096][A-mbU1: 4096][B: 4096]
  auto stage = [&](int tile, int buf) {
    const size_t kOff = (size_t)tile * 4096;
    bf16* d = lds + buf * 12288;
    gload16(aSrc0 + kOff + tEl, d +        wEl);
    gload16(aSrc1 + kOff + tEl, d + 4096 + wEl);
    gload16(bSrc  + kOff + tEl, d + 8192 + wEl);
  };

  f32x4 acc[4][4] = {};   // acc[mi][gate]

  stage(0, 0);
  stage(1, 1);            // 6 loads outstanding

  const int aOff = mbU * 4096 + wm * 2048 + lane * 8;
  const int bOff = 8192 + wn * 2048 + lane * 8;

  auto body = [&](int kt, int p, int pn, bool doStage, bool last) {
    // my tile-kt loads are the 3 oldest; wait for them (tile kt+1's stay out).
    if (last) asm volatile("s_waitcnt vmcnt(0)" ::: "memory");
    else      asm volatile("s_waitcnt vmcnt(3)" ::: "memory");
    __builtin_amdgcn_s_barrier();      // => ALL waves' tile-kt loads landed
    asm volatile("" ::: "memory");
    if (doStage) stage(kt + 2, pn);    // overwrites buf of tile kt-1: its
                                       // reads were consumed (lgkm before
                                       // MFMA) before the previous barrier.
    const bf16* bufA = lds + p * 12288 + aOff;
    const bf16* bufB = lds + p * 12288 + bOff;
    bf16x8 af[4], bfr[4];
#pragma unroll
    for (int i = 0; i < 4; ++i)
      af[i] = *(const bf16x8*)(bufA + i * 512);
#pragma unroll
    for (int g = 0; g < 4; ++g)
      bfr[g] = *(const bf16x8*)(bufB + g * 512);
    __builtin_amdgcn_s_setprio(1);
#pragma unroll
    for (int mi = 0; mi < 4; ++mi)
#pragma unroll
      for (int g = 0; g < 4; ++g)
        acc[mi][g] = __builtin_amdgcn_mfma_f32_16x16x32_bf16(af[mi], bfr[g], acc[mi][g], 0, 0, 0);
    __builtin_amdgcn_s_setprio(0);
  };

#pragma unroll 1
  for (int base = 0; base < 63; base += 3) {
    body(base,     0, 2, base     < 62, false);
    body(base + 1, 1, 0, base + 1 < 62, false);
    body(base + 2, 2, 1, base + 2 < 62, false);
  }
  body(63, 0, 0, false, true);

  // ---- register-resident LSTM epilogue ----
  const int jg = (nb * 2 + wn) * 16 + lrow;
  const int bbase = (nb * 2 + wn) * 64 + lrow;
  const float bi  = Bcomb[bbase +  0];
  const float bf_ = Bcomb[bbase + 16];
  const float bo  = Bcomb[bbase + 32];
  const float bg  = Bcomb[bbase + 48];

#pragma unroll
  for (int mi = 0; mi < 4; ++mi) {
    const int row0 = bm * 256 + mbU * 128 + wm * 64 + mi * 16 + lkg * 4;
    float cv[4];
#pragma unroll
    for (int r = 0; r < 4; ++r)
      cv[r] = c[(size_t)(row0 + r) * 1024 + jg];
#pragma unroll
    for (int r = 0; r < 4; ++r) {
      float zi = acc[mi][0][r] + bi;
      float zf = acc[mi][1][r] + bf_;
      float zo = acc[mi][2][r] + bo;
      float zg = acc[mi][3][r] + bg;
      float it = sigf(zi), ft = sigf(zf), ot = sigf(zo), gt = tanhfast(zg);
      float cn = ft * cv[r] + it * gt;
      size_t off = (size_t)(row0 + r) * 1024 + jg;
      out[off] = ot * tanhfast(cn);        // h_next
      out[CN_OFF + off] = cn;              // c_next
    }
  }
}

extern "C" void kernel_launch(void* const* d_in, const int* in_sizes, int n_in,
                              void* d_out, int out_size, void* d_ws, size_t ws_size,
                              hipStream_t stream) {
  const float* x   = (const float*)d_in[0];
  const float* h   = (const float*)d_in[1];
  const float* c   = (const float*)d_in[2];
  const float* Wxi = (const float*)d_in[3];  const float* bxi = (const float*)d_in[4];
  const float* Whi = (const float*)d_in[5];  const float* bhi = (const float*)d_in[6];
  const float* Wxf = (const float*)d_in[7];  const float* bxf = (const float*)d_in[8];
  const float* Whf = (const float*)d_in[9];  const float* bhf = (const float*)d_in[10];
  const float* Wxo = (const float*)d_in[11]; const float* bxo = (const float*)d_in[12];
  const float* Who = (const float*)d_in[13]; const float* bho = (const float*)d_in[14];
  const float* Wxg = (const float*)d_in[15]; const float* bxg = (const float*)d_in[16];
  const float* Whg = (const float*)d_in[17]; const float* bhg = (const float*)d_in[18];
  float* out = (float*)d_out;

  bf16*  Abuf  = (bf16*)d_ws;                          // 32 MB
  bf16*  Wbuf  = Abuf + (size_t)8192 * 2048;           // 16 MB
  float* Bcomb = (float*)(Wbuf + (size_t)4096 * 2048); // 16 KB

  pack_all<<<4096, 256, 0, stream>>>(x, h,
                                     Wxi, Whi, Wxf, Whf, Wxo, Who, Wxg, Whg,
                                     bxi, bhi, bxf, bhf, bxo, bho, bxg, bhg,
                                     Abuf, Wbuf, Bcomb);
  gemm_lstm<<<1024, 512, 0, stream>>>(Abuf, Wbuf, Bcomb, c, out);
}